// Round 20
// baseline (826.524 us; speedup 1.0000x reference)
//
#include <hip/hip_runtime.h>
#include <hip/hip_bf16.h>

// Problem constants
#define BB   256
#define SS   100
#define DIN  64
#define DD   256
#define HH   8
#define LL   6
#define DFF  1024
#define MM   (BB*SS)          // 25600 rows
#define INV_SCALE 0.17677669529663687f   // 1/sqrt(32)

typedef unsigned short u16;
typedef __attribute__((__ext_vector_type__(8))) __bf16 bf16x8;
typedef __attribute__((__ext_vector_type__(8))) unsigned short u16x8;
typedef __attribute__((__ext_vector_type__(4))) float  f32x4;

__device__ __forceinline__ u16 f2bf(float f) {
    unsigned u = __float_as_uint(f);
    u += 0x7FFFu + ((u >> 16) & 1u);      // RNE
    return (u16)(u >> 16);
}
__device__ __forceinline__ float bf2f(u16 v) {
    return __uint_as_float((unsigned)v << 16);
}

// bijective XCD-chunk swizzle (valid when nb % 8 == 0)
__device__ __forceinline__ int xcd_swz(int bid, int nb) {
    return (nb % 8 == 0) ? (bid % 8) * (nb / 8) + bid / 8 : bid;
}

#define MFMA16(a,b,c) __builtin_amdgcn_mfma_f32_16x16x32_bf16((a),(b),(c),0,0,0)

// async global->LDS, 16B per lane. dest = wave-uniform base + lane*16.
#if defined(__has_builtin)
#if __has_builtin(__builtin_amdgcn_global_load_lds)
#define HAVE_GLDS 1
#endif
#endif

#ifdef HAVE_GLDS
typedef __attribute__((address_space(1))) const void gas_void;
typedef __attribute__((address_space(3))) void las_void;
__device__ __forceinline__ void gload16(const u16* g, u16* l) {
    __builtin_amdgcn_global_load_lds((gas_void*)g, (las_void*)l, 16, 0, 0);
}
#else
__device__ __forceinline__ void gload16(const u16* g, u16* l) {
    const int lane = threadIdx.x & 63;
    *(uint4*)((char*)l + lane * 16) = *(const uint4*)g;
}
#endif

// ---------------------------------------------------------------------------
// Fused prep kernel: pe_init | x->bf16 | 7 weight transposes | bias packs.
// ---------------------------------------------------------------------------
#define PB_PE    0
#define PB_CONV  100
#define PB_WIN   6500
#define PB_WQKV  6516
#define PB_WO    7668
#define PB_W1    8052
#define PB_W2    9588
#define PB_BIAS  11124
#define PB_WH1   11142
#define PB_TOT   11526

__device__ __forceinline__ void do_transpose(const float* __restrict__ in,
                                             u16* __restrict__ out,
                                             int K, int N, long outLstride,
                                             int kb, int nb, int lz,
                                             float (*tile)[33]) {
    const int k0 = kb * 32, n0 = nb * 32;
    const int tx = threadIdx.x & 31, ty = threadIdx.x >> 5;
    const float* src = in + (size_t)lz * K * N;
#pragma unroll
    for (int i = 0; i < 4; ++i)
        tile[ty + i*8][tx] = src[(size_t)(k0 + ty + i*8) * N + n0 + tx];
    __syncthreads();
    u16* dst = out + (size_t)lz * outLstride;
#pragma unroll
    for (int i = 0; i < 4; ++i)
        dst[(size_t)(n0 + ty + i*8) * K + k0 + tx] = f2bf(tile[tx][ty + i*8]);
}

__global__ __launch_bounds__(256)
void prep_all(const float* __restrict__ x,    const float* __restrict__ W_in,
              const float* __restrict__ Wq,   const float* __restrict__ Wk,
              const float* __restrict__ Wv,   const float* __restrict__ Wo,
              const float* __restrict__ W1,   const float* __restrict__ W2,
              const float* __restrict__ bq,   const float* __restrict__ bk,
              const float* __restrict__ bv,
              const float* __restrict__ Wr1,  const float* __restrict__ Wa1,
              const float* __restrict__ Wc1,  const float* __restrict__ Wv1,
              const float* __restrict__ br1,  const float* __restrict__ ba1,
              const float* __restrict__ bc1,  const float* __restrict__ bv1,
              float* __restrict__ pe, u16* __restrict__ xb,
              u16* __restrict__ WinT, u16* __restrict__ WqkvT,
              u16* __restrict__ WoT,  u16* __restrict__ W1T,
              u16* __restrict__ W2T,  float* __restrict__ bqkv,
              u16* __restrict__ Wh1T, float* __restrict__ bh1) {
    __shared__ float tile[32][33];
    const int b0 = blockIdx.x;
    const int t = threadIdx.x;

    if (b0 < PB_CONV) {                       // pe_init: 100 blocks
        int i = b0 * 256 + t;
        int s = i >> 8, c = i & 255, ce = c & ~1;
        double div = exp((double)ce * -0.03597789207803197);
        double ang = (double)s * div;
        pe[i] = (float)((c & 1) ? cos(ang) : sin(ang));
    } else if (b0 < PB_WIN) {                 // conv_bf16: 6400 blocks
        int i = (b0 - PB_CONV) * 256 + t;
        xb[i] = f2bf(x[i]);
    } else if (b0 < PB_WQKV) {                // W_in^T: 16 blocks (2 x 8)
        int r = b0 - PB_WIN;
        do_transpose(W_in, WinT, DIN, DD, (long)DIN * DD, r % 2, r / 2, 0, tile);
    } else if (b0 < PB_WO) {                  // Wq|Wk|Wv^T: 1152 (3 x 8x8x6)
        int idx = b0 - PB_WQKV;
        int which = idx / 384, r = idx % 384;
        const float* src = (which == 0) ? Wq : (which == 1) ? Wk : Wv;
        do_transpose(src, WqkvT + (size_t)which * DD * DD, DD, DD, 768L * DD,
                     r % 8, (r / 8) % 8, r / 64, tile);
    } else if (b0 < PB_W1) {                  // Wo^T: 384 (8x8x6)
        int r = b0 - PB_WO;
        do_transpose(Wo, WoT, DD, DD, (long)DD * DD, r % 8, (r / 8) % 8, r / 64, tile);
    } else if (b0 < PB_W2) {                  // W1^T: 1536 (8x32x6)
        int r = b0 - PB_W1;
        do_transpose(W1, W1T, DD, DFF, (long)DD * DFF, r % 8, (r / 8) % 32, r / 256, tile);
    } else if (b0 < PB_BIAS) {                // W2^T: 1536 (32x8x6)
        int r = b0 - PB_W2;
        do_transpose(W2, W2T, DFF, DD, (long)DD * DFF, r % 32, (r / 32) % 8, r / 256, tile);
    } else if (b0 < PB_WH1) {                 // pack_bias: 18 blocks
        int idx = (b0 - PB_BIAS) * 256 + t;
        if (idx < LL * 768) {
            int l = idx / 768, c = idx % 768;
            float v = (c < 256) ? bq[l*256 + c] : (c < 512) ? bk[l*256 + c - 256]
                                                            : bv[l*256 + c - 512];
            bqkv[idx] = v;
        }
    } else {                                  // pack_wh1: 384 blocks
        int i = (b0 - PB_WH1) * 256 + t;
        if (i < 384 * 256) {
            int n = i >> 8, k = i & 255;
            float v = (n < 128) ? Wr1[k*128 + n]
                    : (n < 256) ? Wa1[k*128 + (n-128)]
                    : (n < 320) ? Wc1[k*64  + (n-256)]
                                : Wv1[k*64  + (n-320)];
            Wh1T[(size_t)n * 256 + k] = f2bf(v);
        }
        if (i < 384) {
            float v = (i < 128) ? br1[i] : (i < 256) ? ba1[i-128]
                    : (i < 320) ? bc1[i-256] : bv1[i-320];
            bh1[i] = v;
        }
    }
}

// ---------------------------------------------------------------------------
// Single-barrier rotating depth-3 counted-vmcnt bf16 MFMA GEMM (T3+T4):
//   C = epi(A[M,K] @ Wt[N,K]^T + bias)
// 128x128 tile, 2x2 waves (64x64 each), BK=32, chunk-XOR swizzled LDS,
// setprio MFMA, XCD-swizzled grid.
// Loop: wait vmcnt(counted) -> ONE barrier -> restage buffer consumed LAST
// iter (issue EARLY: 2 compute phases of latency cover before its wait) ->
// ds_read+MFMA.  vmcnt(0) only on final tile.
// EPI: 0=bias, 1=bias+relu, 2=bias+PE.
// ---------------------------------------------------------------------------
template<int EPI, bool OF32, bool OBF16>
__global__ __launch_bounds__(256)
void mfma_gemm(const u16* __restrict__ A, const u16* __restrict__ Wt,
               const float* __restrict__ bias, const float* __restrict__ pe,
               float* __restrict__ Cf, u16* __restrict__ Cb,
               int M, int N, int K) {
    __shared__ u16 As[3][128 * 32];
    __shared__ u16 Bs[3][128 * 32];
    const int t = threadIdx.x, w = t >> 6, l = t & 63;
    const int bx = xcd_swz(blockIdx.x, gridDim.x);
    const int bm = bx * 128, bn = blockIdx.y * 128;
    const int wr = (w >> 1) * 64, wc = (w & 1) * 64;
    const int lr = l & 15, lq = (l >> 4) * 4;
    const int lks = (((l >> 4) ^ ((lr >> 1) & 3)) * 8);
    const int srow = l >> 2, scol = (((l & 3) ^ ((l >> 3) & 3)) * 8);

    f32x4 acc[4][4] = {};
    const u16* Ag = &A [(size_t)(bm + w * 32 + srow) * K + scol];
    const u16* Bg = &Wt[(size_t)(bn + w * 32 + srow) * K + scol];

    auto stage = [&](int buf, int k0) {   // 4 loads per wave per stage
        gload16(Ag + k0,                  &As[buf][(w * 32) * 32]);
        gload16(Ag + k0 + (size_t)16 * K, &As[buf][(w * 32 + 16) * 32]);
        gload16(Bg + k0,                  &Bs[buf][(w * 32) * 32]);
        gload16(Bg + k0 + (size_t)16 * K, &Bs[buf][(w * 32 + 16) * 32]);
    };

    const int tiles = K >> 5;
    stage(0, 0);
    if (tiles > 1) stage(1, 32);
    if (tiles > 2) stage(2, 64);
    int cur = 0;

    for (int i = 0; i < tiles; ++i) {
        const int k0 = i << 5;
        if (i == tiles - 1)      asm volatile("s_waitcnt vmcnt(0)" ::: "memory");
        else if (i == 0) {
            if (tiles > 2)       asm volatile("s_waitcnt vmcnt(8)" ::: "memory");
            else                 asm volatile("s_waitcnt vmcnt(4)" ::: "memory");
        } else                   asm volatile("s_waitcnt vmcnt(4)" ::: "memory");
        __builtin_amdgcn_s_barrier();      // cur landed everywhere; prev free

        // restage buffer consumed last iter with tile i+2 (issue EARLY,
        // before this iter's compute: ~2 compute phases of latency cover)
        if (i >= 1 && k0 + 64 < K) stage((cur + 2) % 3, k0 + 64);

        bf16x8 af[4], bfr[4];
#pragma unroll
        for (int m = 0; m < 4; ++m) af[m]  = *(const bf16x8*)&As[cur][(wr + m*16 + lr) * 32 + lks];
#pragma unroll
        for (int n = 0; n < 4; ++n) bfr[n] = *(const bf16x8*)&Bs[cur][(wc + n*16 + lr) * 32 + lks];
        __builtin_amdgcn_s_setprio(1);
#pragma unroll
        for (int m = 0; m < 4; ++m)
#pragma unroll
            for (int n = 0; n < 4; ++n)
                acc[m][n] = MFMA16(af[m], bfr[n], acc[m][n]);
        __builtin_amdgcn_s_setprio(0);

        cur = (cur == 2) ? 0 : cur + 1;
    }

    // C/D layout: col=lane&15, row=(lane>>4)*4+j
#pragma unroll
    for (int n = 0; n < 4; ++n) {
        const int col = bn + wc + n*16 + lr;
        const float bv = bias[col];
#pragma unroll
        for (int m = 0; m < 4; ++m) {
#pragma unroll
            for (int j = 0; j < 4; ++j) {
                const int row = bm + wr + m*16 + lq + j;
                float v = acc[m][n][j] + bv;
                if (EPI == 1) v = fmaxf(v, 0.f);
                if (EPI == 2) v += pe[(row % SS) * DD + col];
                if (OF32)  Cf[(size_t)row * N + col] = v;
                if (OBF16) Cb[(size_t)row * N + col] = f2bf(v);
            }
        }
    }
}

// ---------------------------------------------------------------------------
// Single-barrier rotating depth-3 fused GEMM + bias + residual + LN,
// 8 waves (512 thr), chunk-XOR swizzled LDS, setprio, XCD swizzle:
//   y = LN(bf16_resid + A@Wt^T + bias)*g + be -> hb (bf16, sole stream)
// Tile 64 rows x 256 cols, wave grid 2x4 (each wave 32x64, acc 2x4).
// Staging: 20 chunks (A:4, B:16); waves 0-3 stage 3, waves 4-7 stage 2.
// Restage issued EARLY (right after barrier) for 2-phase latency cover.
// ---------------------------------------------------------------------------
__global__ __launch_bounds__(512)
void gemm_ln(const u16* __restrict__ A, const u16* __restrict__ Wt,
             const float* __restrict__ bias, const float* __restrict__ g,
             const float* __restrict__ be, u16* __restrict__ hb, int K) {
    __shared__ u16 As[3][64 * 32];
    __shared__ u16 Bs[3][256 * 32];
    __shared__ float red[64][8];   // [row][wc*2 + {s1,s2}]
    const int t = threadIdx.x, w = t >> 6, l = t & 63;
    const int bm = xcd_swz(blockIdx.x, gridDim.x) * 64;
    const int wr = w >> 2, wc = w & 3;
    const int lr = l & 15, lq = (l >> 4) * 4;
    const int lks = (((l >> 4) ^ ((lr >> 1) & 3)) * 8);
    const int crow = l >> 2, ccol = (((l & 3) ^ ((l >> 3) & 3)) * 8);

    // staging chunk assignment (wave-uniform): waves 0-3 -> 3 chunks, 4-7 -> 2
    const int c0 = (w < 4) ? 3*w : 12 + 2*(w - 4);
    const int nc = (w < 4) ? 3 : 2;

    f32x4 acc[2][4] = {};

    auto stage = [&](int buf, int k0) {
        for (int ci = 0; ci < nc; ++ci) {
            const int c = c0 + ci;
            if (c < 4)
                gload16(&A [(size_t)(bm + c*16 + crow) * K + k0 + ccol], &As[buf][c*16*32]);
            else
                gload16(&Wt[(size_t)((c-4)*16 + crow) * K + k0 + ccol], &Bs[buf][(c-4)*16*32]);
        }
    };

    const int tiles = K >> 5;
    stage(0, 0);
    if (tiles > 1) stage(1, 32);
    if (tiles > 2) stage(2, 64);
    int cur = 0;

    for (int i = 0; i < tiles; ++i) {
        const int k0 = i << 5;
        if (i == tiles - 1) {
            asm volatile("s_waitcnt vmcnt(0)" ::: "memory");
        } else if (i == 0 && tiles > 2) {
            if (w < 4) asm volatile("s_waitcnt vmcnt(6)" ::: "memory");
            else       asm volatile("s_waitcnt vmcnt(4)" ::: "memory");
        } else {
            if (w < 4) asm volatile("s_waitcnt vmcnt(3)" ::: "memory");
            else       asm volatile("s_waitcnt vmcnt(2)" ::: "memory");
        }
        __builtin_amdgcn_s_barrier();      // cur landed everywhere; prev free

        if (i >= 1 && k0 + 64 < K) stage((cur + 2) % 3, k0 + 64);   // early

        bf16x8 af[2], bf[4];
#pragma unroll
        for (int mf = 0; mf < 2; ++mf) af[mf] = *(const bf16x8*)&As[cur][(wr*32 + mf*16 + lr) * 32 + lks];
#pragma unroll
        for (int n = 0; n < 4; ++n)    bf[n]  = *(const bf16x8*)&Bs[cur][(wc*64 + n*16 + lr) * 32 + lks];
        __builtin_amdgcn_s_setprio(1);
#pragma unroll
        for (int mf = 0; mf < 2; ++mf)
#pragma unroll
            for (int n = 0; n < 4; ++n)
                acc[mf][n] = MFMA16(af[mf], bf[n], acc[mf][n]);
        __builtin_amdgcn_s_setprio(0);

        cur = (cur == 2) ? 0 : cur + 1;
    }

    float bv[4], gv[4], bev[4];
#pragma unroll
    for (int n = 0; n < 4; ++n) {
        int col = wc*64 + n*16 + lr;
        bv[n] = bias[col]; gv[n] = g[col]; bev[n] = be[col];
    }
    // pass 1: add bias + bf16 residual, partial row sums over wave's 64 cols
#pragma unroll
    for (int mf = 0; mf < 2; ++mf) {
#pragma unroll
        for (int j = 0; j < 4; ++j) {
            const int rloc = wr*32 + mf*16 + lq + j;
            const int row  = bm + rloc;
            float s1 = 0.f, s2 = 0.f;
#pragma unroll
            for (int n = 0; n < 4; ++n) {
                float v = acc[mf][n][j] + bv[n] + bf2f(hb[(size_t)row * DD + wc*64 + n*16 + lr]);
                acc[mf][n][j] = v;
                s1 += v; s2 += v * v;
            }
            s1 += __shfl_xor(s1, 1); s2 += __shfl_xor(s2, 1);
            s1 += __shfl_xor(s1, 2); s2 += __shfl_xor(s2, 2);
            s1 += __shfl_xor(s1, 4); s2 += __shfl_xor(s2, 4);
            s1 += __shfl_xor(s1, 8); s2 += __shfl_xor(s2, 8);
            if (lr == 0) { red[rloc][wc*2] = s1; red[rloc][wc*2+1] = s2; }
        }
    }
    __syncthreads();
    // pass 2: normalize + store bf16
#pragma unroll
    for (int mf = 0; mf < 2; ++mf) {
#pragma unroll
        for (int j = 0; j < 4; ++j) {
            const int rloc = wr*32 + mf*16 + lq + j;
            const int row  = bm + rloc;
            float s1 = red[rloc][0] + red[rloc][2] + red[rloc][4] + red[rloc][6];
            float s2 = red[rloc][1] + red[rloc][3] + red[rloc][5] + red[rloc][7];
            float mean = s1 * (1.f/DD);
            float var  = s2 * (1.f/DD) - mean*mean;
            float rstd = rsqrtf(var + 1e-5f);
#pragma unroll
            for (int n = 0; n < 4; ++n) {
                int col = wc*64 + n*16 + lr;
                float y = (acc[mf][n][j] - mean) * rstd * gv[n] + bev[n];
                hb[(size_t)row * DD + col] = f2bf(y);
            }
        }
    }
}

// ---------------------------------------------------------------------------
// MFMA attention: one block per (b,h), 4 waves (wave w owns q-rows 32w..32w+32).
// Q/K frags straight from global. V transposed to LDS via coalesced loads.
// ---------------------------------------------------------------------------
__global__ __launch_bounds__(256)
void attn_mfma(const u16* __restrict__ qkv, u16* __restrict__ ao) {
    const int b = blockIdx.x >> 3, hh = blockIdx.x & 7;
    const int t = threadIdx.x, w = t >> 6, l = t & 63;
    const int lr = l & 15, lk = (l >> 4) * 8, lq = (l >> 4) * 4;
    __shared__ u16 Vt[32 * 136];          // V^T[d][s], s padded/zeroed to 136
    __shared__ u16 Ps[4][32 * 136];
    const size_t rbase = (size_t)b * SS * 768;
    const int qc = hh * 32, kc = 256 + hh * 32, vc = 512 + hh * 32;

    // V stage: coalesced row loads, transpose in regs -> LDS
    for (int u = t; u < 400; u += 256) {           // 100 rows x 4 chunks of 8
        int s = u >> 2, dp = (u & 3) * 8;
        u16x8 vv = *(const u16x8*)&qkv[rbase + (size_t)s * 768 + vc + dp];
#pragma unroll
        for (int e = 0; e < 8; ++e) Vt[(dp + e) * 136 + s] = vv[e];
    }
    for (int i = t; i < 32 * 36; i += 256) {       // zero pad s=100..135
        int d = i / 36, s2 = 100 + i % 36;
        Vt[d * 136 + s2] = 0;
    }

    // Q fragments direct from global
    u16x8 qz = {0,0,0,0,0,0,0,0};
    u16x8 qfr[2];
#pragma unroll
    for (int m = 0; m < 2; ++m) {
        int r = w * 32 + m * 16 + lr;
        qfr[m] = (r < SS) ? *(const u16x8*)&qkv[rbase + (size_t)r * 768 + qc + lk] : qz;
    }

    // S = Q K^T
    f32x4 sacc[2][7] = {};
#pragma unroll
    for (int n = 0; n < 7; ++n) {
        int r = n * 16 + lr;
        u16x8 kfr = (r < SS) ? *(const u16x8*)&qkv[rbase + (size_t)r * 768 + kc + lk] : qz;
#pragma unroll
        for (int m = 0; m < 2; ++m)
            sacc[m][n] = MFMA16(*(bf16x8*)&qfr[m], *(bf16x8*)&kfr, sacc[m][n]);
    }

    // softmax per row (cols n*16+lr; cols>=100 masked)
#pragma unroll
    for (int m = 0; m < 2; ++m) {
#pragma unroll
        for (int j = 0; j < 4; ++j) {
            float mx = -1e30f;
#pragma unroll
            for (int n = 0; n < 7; ++n) {
                float s = sacc[m][n][j] * INV_SCALE;
                if (n == 6 && lr >= 4) s = -1e30f;
                sacc[m][n][j] = s;
                mx = fmaxf(mx, s);
            }
            mx = fmaxf(mx, __shfl_xor(mx, 1));
            mx = fmaxf(mx, __shfl_xor(mx, 2));
            mx = fmaxf(mx, __shfl_xor(mx, 4));
            mx = fmaxf(mx, __shfl_xor(mx, 8));
            float sum = 0.f;
#pragma unroll
            for (int n = 0; n < 7; ++n) {
                float p = expf(sacc[m][n][j] - mx);
                if (n == 6 && lr >= 4) p = 0.f;
                sacc[m][n][j] = p;
                sum += p;
            }
            sum += __shfl_xor(sum, 1);
            sum += __shfl_xor(sum, 2);
            sum += __shfl_xor(sum, 4);
            sum += __shfl_xor(sum, 8);
            float inv = 1.f / sum;
#pragma unroll
            for (int n = 0; n < 7; ++n) sacc[m][n][j] *= inv;
        }
    }

    // P -> LDS (bf16), wave-private; zero pad cols 112..135
    u16* myP = &Ps[w][0];
    for (int i = l; i < 32 * 24; i += 64) {
        int r = i / 24, c2 = 112 + i % 24;
        myP[r * 136 + c2] = 0;
    }
#pragma unroll
    for (int m = 0; m < 2; ++m)
#pragma unroll
        for (int n = 0; n < 7; ++n)
#pragma unroll
            for (int j = 0; j < 4; ++j)
                myP[(m*16 + lq + j) * 136 + n*16 + lr] = f2bf(sacc[m][n][j]);

    __syncthreads();   // Vt + Ps visible

    // O = P @ V
    f32x4 oacc[2][2] = {};
#pragma unroll
    for (int ks = 0; ks < 4; ++ks) {
        bf16x8 pf[2], vf[2];
#pragma unroll
        for (int m = 0; m < 2; ++m) pf[m] = *(const bf16x8*)&myP[(m*16 + lr) * 136 + ks*32 + lk];
#pragma unroll
        for (int n = 0; n < 2; ++n) vf[n] = *(const bf16x8*)&Vt [(n*16 + lr) * 136 + ks*32 + lk];
#pragma unroll
        for (int m = 0; m < 2; ++m)
#pragma unroll
            for (int n = 0; n < 2; ++n)
                oacc[m][n] = MFMA16(pf[m], vf[n], oacc[m][n]);
    }
#pragma unroll
    for (int m = 0; m < 2; ++m)
#pragma unroll
        for (int j = 0; j < 4; ++j) {
            int s = w*32 + m*16 + lq + j;
            if (s < SS) {
#pragma unroll
                for (int n = 0; n < 2; ++n)
                    ao[((size_t)(b*SS + s)) * DD + hh*32 + n*16 + lr] = f2bf(oacc[m][n][j]);
            }
        }
}

// ---------------------------------------------------------------------------
// Final LN on last row of each batch only (reads bf16 hb, stats in fp32).
// ---------------------------------------------------------------------------
__global__ __launch_bounds__(256)
void lastrow_ln(const u16* __restrict__ hb, const float* __restrict__ g,
                const float* __restrict__ be, float* __restrict__ out,
                u16* __restrict__ hfb) {
    const int b = blockIdx.x;
    const int c = threadIdx.x;
    float x = bf2f(hb[(size_t)(b * SS + SS - 1) * DD + c]);

    float s1 = x, s2 = x * x;
#pragma unroll
    for (int o = 32; o > 0; o >>= 1) {
        s1 += __shfl_down(s1, o);
        s2 += __shfl_down(s2, o);
    }
    __shared__ float w1[4], w2[4];
    __shared__ float mean_s, rstd_s;
    const int wid = c >> 6, lane = c & 63;
    if (lane == 0) { w1[wid] = s1; w2[wid] = s2; }
    __syncthreads();
    if (c == 0) {
        float t1 = w1[0] + w1[1] + w1[2] + w1[3];
        float t2 = w2[0] + w2[1] + w2[2] + w2[3];
        float m = t1 * (1.0f / DD);
        float v = t2 * (1.0f / DD) - m * m;
        mean_s = m;
        rstd_s = rsqrtf(v + 1e-5f);
    }
    __syncthreads();
    float y = (x - mean_s) * rstd_s * g[c] + be[c];
    out[1536 + b * DD + c] = y;
    hfb[b * DD + c] = f2bf(y);
}

// ---------------------------------------------------------------------------
// Heads layer-2+: reads t1f[b][384] = relu([r1|a1|c1|v1]), finishes all heads.
// ---------------------------------------------------------------------------
__global__ __launch_bounds__(256)
void heads2_kernel(const float* __restrict__ t1f,
                   const float* __restrict__ Wr2, const float* __restrict__ br2,
                   const float* __restrict__ Wa2, const float* __restrict__ ba2,
                   const float* __restrict__ Wa3, const float* __restrict__ ba3,
                   const float* __restrict__ Wc2, const float* __restrict__ bc2,
                   const float* __restrict__ Wv2, const float* __restrict__ bv2,
                   float* __restrict__ out) {
    const int b = blockIdx.x, t = threadIdx.x;
    __shared__ float t1[384];
    __shared__ float a2[64];
    __shared__ float lg[3];
    for (int i = t; i < 384; i += 256) t1[i] = t1f[(size_t)b * 384 + i];
    __syncthreads();

    if (t < 64) {                       // action layer 2 (128 -> 64), relu
        float acc = ba2[t];
        for (int k = 0; k < 128; ++k) acc = fmaf(t1[128 + k], Wa2[k * 64 + t], acc);
        a2[t] = fmaxf(acc, 0.f);
    } else if (t == 64) {               // confidence (64 -> 1), sigmoid
        float acc = bc2[0];
        for (int k = 0; k < 64; ++k) acc = fmaf(t1[256 + k], Wc2[k], acc);
        out[1024 + b] = 1.0f / (1.0f + expf(-acc));
    } else if (t == 65) {               // volatility (64 -> 1), relu
        float acc = bv2[0];
        for (int k = 0; k < 64; ++k) acc = fmaf(t1[320 + k], Wv2[k], acc);
        out[1280 + b] = fmaxf(acc, 0.f);
    } else if (t >= 66 && t < 69) {     // regime logits (128 -> 3)
        int r = t - 66;
        float acc = br2[r];
        for (int k = 0; k < 128; ++k) acc = fmaf(t1[k], Wr2[k * 3 + r], acc);
        lg[r] = acc;
    }
    __syncthreads();
    if (t == 0) {                       // regime softmax
        float m = fmaxf(lg[0], fmaxf(lg[1], lg[2]));
        float e0 = expf(lg[0] - m), e1 = expf(lg[1] - m), e2 = expf(lg[2] - m);
        float inv = 1.0f / (e0 + e1 + e2);
        out[256 + b * 3 + 0] = e0 * inv;
        out[256 + b * 3 + 1] = e1 * inv;
        out[256 + b * 3 + 2] = e2 * inv;
    }
    if (t < 64) {                       // action layer 3 (64 -> 1), tanh
        float p = a2[t] * Wa3[t];
        p += __shfl_xor(p, 1);
        p += __shfl_xor(p, 2);
        p += __shfl_xor(p, 4);
        p += __shfl_xor(p, 8);
        p += __shfl_xor(p, 16);
        p += __shfl_xor(p, 32);
        if (t == 0) out[b] = tanhf(p + ba3[0]);
    }
}

// ---------------------------------------------------------------------------
// Launch
// ---------------------------------------------------------------------------
extern "C" void kernel_launch(void* const* d_in, const int* in_sizes, int n_in,
                              void* d_out, int out_size, void* d_ws, size_t ws_size,
                              hipStream_t stream) {
    const float* x    = (const float*)d_in[0];
    const float* W_in = (const float*)d_in[1];
    const float* b_in = (const float*)d_in[2];
    const float* Wq   = (const float*)d_in[3];
    const float* bq   = (const float*)d_in[4];
    const float* Wk   = (const float*)d_in[5];
    const float* bk   = (const float*)d_in[6];
    const float* Wv   = (const float*)d_in[7];
    const float* bv   = (const float*)d_in[8];
    const float* Wo   = (const float*)d_in[9];
    const float* bo   = (const float*)d_in[10];
    const float* g1   = (const float*)d_in[11];
    const float* be1  = (const float*)d_in[12];
    const float* W1   = (const float*)d_in[13];
    const float* b1   = (const float*)d_in[14];
    const float* W2   = (const float*)d_in[15];
    const float* b2   = (const float*)d_in[16];
    const float* g2   = (const float*)d_in[17];
    const float* be2  = (const float*)d_in[18];
    const float* lnf_g = (const float*)d_in[19];
    const float* lnf_b = (const float*)d_in[20];
    const float* Wr1  = (const float*)d_in[21];
    const float* br1  = (const float*)d_in[22];
    const float* Wr2  = (const float*)d_in[23];
    const float* br2  = (const float*)d_in[24];
    const float* Wa1  = (const float*)d_in[25];
    const float* ba1  = (const float*)d_in[26];
    const float* Wa2  = (const float*)d_in[27];
    const float* ba2  = (const float*)d_in[28];
    const float* Wa3  = (const float*)d_in[29];
    const float* ba3  = (const float*)d_in[30];
    const float* Wc1  = (const float*)d_in[31];
    const float* bc1  = (const float*)d_in[32];
    const float* Wc2  = (const float*)d_in[33];
    const float* bc2  = (const float*)d_in[34];
    const float* Wv1  = (const float*)d_in[35];
    const float* bv1  = (const float*)d_in[36];
    const float* Wv2  = (const float*)d_in[37];
    const float* bv2  = (const float*)d_in[38];
    float* out = (float*)d_out;

    // workspace layout
    char* w8 = (char*)d_ws;
    float* pe    = (float*)w8;  w8 += (size_t)SS * DD * 4;
    u16*   hb    = (u16*)w8;    w8 += (size_t)MM * DD * 2;
    u16*   xb    = (u16*)w8;    w8 += (size_t)MM * DIN * 2;
    u16*   qkvb  = (u16*)w8;    w8 += (size_t)MM * 768 * 2;
    u16*   ao    = (u16*)w8;    w8 += (size_t)MM * DD * 2;
    u16*   ffn1b = (u16*)w8;    w8 += (size_t)MM * DFF * 2;
    u16*   WinT  = (u16*)w8;    w8 += (size_t)DIN * DD * 2;
    u16*   WqkvT = (u16*)w8;    w8 += (size_t)LL * 768 * DD * 2;
    u16*   WoT   = (u16*)w8;    w8 += (size_t)LL * DD * DD * 2;
    u16*   W1T   = (u16*)w8;    w8 += (size_t)LL * DFF * DD * 2;
    u16*   W2T   = (u16*)w8;    w8 += (size_t)LL * DD * DFF * 2;
    float* bqkv  = (float*)w8;  w8 += (size_t)LL * 768 * 4;
    u16*   Wh1T  = (u16*)w8;    w8 += (size_t)384 * 256 * 2;
    float* bh1   = (float*)w8;  w8 += (size_t)384 * 4;
    u16*   hfb   = (u16*)w8;    w8 += (size_t)BB * DD * 2;
    float* t1f   = (float*)w8;  w8 += (size_t)BB * 384 * 4;

    // fused prep (replaces 11 serial dispatches)
    prep_all<<<PB_TOT, 256, 0, stream>>>(
        x, W_in, Wq, Wk, Wv, Wo, W1, W2, bq, bk, bv,
        Wr1, Wa1, Wc1, Wv1, br1, ba1, bc1, bv1,
        pe, xb, WinT, WqkvT, WoT, W1T, W2T, bqkv, Wh1T, bh1);

    // input projection + PE  -> hb (bf16 residual stream)
    mfma_gemm<2, false, true><<<dim3(MM/128, DD/128), 256, 0, stream>>>(
        xb, WinT, b_in, pe, nullptr, hb, MM, DD, DIN);

    for (int l = 0; l < LL; ++l) {
        mfma_gemm<0, false, true><<<dim3(MM/128, 768/128), 256, 0, stream>>>(
            hb, WqkvT + (size_t)l*768*DD, bqkv + l*768, nullptr, nullptr, qkvb, MM, 768, DD);
        attn_mfma<<<BB * HH, 256, 0, stream>>>(qkvb, ao);
        gemm_ln<<<MM/64, 512, 0, stream>>>(
            ao, WoT + (size_t)l*DD*DD, bo + l*DD, g1 + l*DD, be1 + l*DD, hb, DD);
        mfma_gemm<1, false, true><<<dim3(MM/128, DFF/128), 256, 0, stream>>>(
            hb, W1T + (size_t)l*DFF*DD, b1 + l*DFF, nullptr, nullptr, ffn1b, MM, DFF, DD);
        gemm_ln<<<MM/64, 512, 0, stream>>>(
            ffn1b, W2T + (size_t)l*DD*DFF, b2 + l*DD, g2 + l*DD, be2 + l*DD, hb, DFF);
    }

    // final LN: only the last row per batch is consumed downstream
    lastrow_ln<<<BB, 256, 0, stream>>>(hb, lnf_g, lnf_b, out, hfb);

    // heads layer 1 as one MFMA GEMM (relu): [256,256] @ [256,384]^T
    mfma_gemm<1, true, false><<<dim3(2, 3), 256, 0, stream>>>(
        hfb, Wh1T, bh1, nullptr, t1f, nullptr, 256, 384, 256);

    // heads layer 2+
    heads2_kernel<<<BB, 256, 0, stream>>>(t1f,
        Wr2, br2, Wa2, ba2, Wa3, ba3, Wc2, bc2, Wv2, bv2, out);
}

// Round 21
// 813.432 us; speedup vs baseline: 1.0161x; 1.0161x over previous
//
#include <hip/hip_runtime.h>
#include <hip/hip_bf16.h>

// Problem constants
#define BB   256
#define SS   100
#define DIN  64
#define DD   256
#define HH   8
#define LL   6
#define DFF  1024
#define MM   (BB*SS)          // 25600 rows
#define INV_SCALE 0.17677669529663687f   // 1/sqrt(32)

typedef unsigned short u16;
typedef __attribute__((__ext_vector_type__(8))) __bf16 bf16x8;
typedef __attribute__((__ext_vector_type__(8))) unsigned short u16x8;
typedef __attribute__((__ext_vector_type__(4))) float  f32x4;

__device__ __forceinline__ u16 f2bf(float f) {
    unsigned u = __float_as_uint(f);
    u += 0x7FFFu + ((u >> 16) & 1u);      // RNE
    return (u16)(u >> 16);
}
__device__ __forceinline__ float bf2f(u16 v) {
    return __uint_as_float((unsigned)v << 16);
}

// bijective XCD-chunk swizzle (valid when nb % 8 == 0)
__device__ __forceinline__ int xcd_swz(int bid, int nb) {
    return (nb % 8 == 0) ? (bid % 8) * (nb / 8) + bid / 8 : bid;
}

#define MFMA16(a,b,c) __builtin_amdgcn_mfma_f32_16x16x32_bf16((a),(b),(c),0,0,0)

// async global->LDS, 16B per lane. dest = wave-uniform base + lane*16.
#if defined(__has_builtin)
#if __has_builtin(__builtin_amdgcn_global_load_lds)
#define HAVE_GLDS 1
#endif
#endif

#ifdef HAVE_GLDS
typedef __attribute__((address_space(1))) const void gas_void;
typedef __attribute__((address_space(3))) void las_void;
__device__ __forceinline__ void gload16(const u16* g, u16* l) {
    __builtin_amdgcn_global_load_lds((gas_void*)g, (las_void*)l, 16, 0, 0);
}
#else
__device__ __forceinline__ void gload16(const u16* g, u16* l) {
    const int lane = threadIdx.x & 63;
    *(uint4*)((char*)l + lane * 16) = *(const uint4*)g;
}
#endif

// ---------------------------------------------------------------------------
// Fused prep kernel: pe_init | x->bf16 | 7 weight transposes | bias packs.
// ---------------------------------------------------------------------------
#define PB_PE    0
#define PB_CONV  100
#define PB_WIN   6500
#define PB_WQKV  6516
#define PB_WO    7668
#define PB_W1    8052
#define PB_W2    9588
#define PB_BIAS  11124
#define PB_WH1   11142
#define PB_TOT   11526

__device__ __forceinline__ void do_transpose(const float* __restrict__ in,
                                             u16* __restrict__ out,
                                             int K, int N, long outLstride,
                                             int kb, int nb, int lz,
                                             float (*tile)[33]) {
    const int k0 = kb * 32, n0 = nb * 32;
    const int tx = threadIdx.x & 31, ty = threadIdx.x >> 5;
    const float* src = in + (size_t)lz * K * N;
#pragma unroll
    for (int i = 0; i < 4; ++i)
        tile[ty + i*8][tx] = src[(size_t)(k0 + ty + i*8) * N + n0 + tx];
    __syncthreads();
    u16* dst = out + (size_t)lz * outLstride;
#pragma unroll
    for (int i = 0; i < 4; ++i)
        dst[(size_t)(n0 + ty + i*8) * K + k0 + tx] = f2bf(tile[tx][ty + i*8]);
}

__global__ __launch_bounds__(256)
void prep_all(const float* __restrict__ x,    const float* __restrict__ W_in,
              const float* __restrict__ Wq,   const float* __restrict__ Wk,
              const float* __restrict__ Wv,   const float* __restrict__ Wo,
              const float* __restrict__ W1,   const float* __restrict__ W2,
              const float* __restrict__ bq,   const float* __restrict__ bk,
              const float* __restrict__ bv,
              const float* __restrict__ Wr1,  const float* __restrict__ Wa1,
              const float* __restrict__ Wc1,  const float* __restrict__ Wv1,
              const float* __restrict__ br1,  const float* __restrict__ ba1,
              const float* __restrict__ bc1,  const float* __restrict__ bv1,
              float* __restrict__ pe, u16* __restrict__ xb,
              u16* __restrict__ WinT, u16* __restrict__ WqkvT,
              u16* __restrict__ WoT,  u16* __restrict__ W1T,
              u16* __restrict__ W2T,  float* __restrict__ bqkv,
              u16* __restrict__ Wh1T, float* __restrict__ bh1) {
    __shared__ float tile[32][33];
    const int b0 = blockIdx.x;
    const int t = threadIdx.x;

    if (b0 < PB_CONV) {                       // pe_init: 100 blocks
        int i = b0 * 256 + t;
        int s = i >> 8, c = i & 255, ce = c & ~1;
        double div = exp((double)ce * -0.03597789207803197);
        double ang = (double)s * div;
        pe[i] = (float)((c & 1) ? cos(ang) : sin(ang));
    } else if (b0 < PB_WIN) {                 // conv_bf16: 6400 blocks
        int i = (b0 - PB_CONV) * 256 + t;
        xb[i] = f2bf(x[i]);
    } else if (b0 < PB_WQKV) {                // W_in^T: 16 blocks (2 x 8)
        int r = b0 - PB_WIN;
        do_transpose(W_in, WinT, DIN, DD, (long)DIN * DD, r % 2, r / 2, 0, tile);
    } else if (b0 < PB_WO) {                  // Wq|Wk|Wv^T: 1152 (3 x 8x8x6)
        int idx = b0 - PB_WQKV;
        int which = idx / 384, r = idx % 384;
        const float* src = (which == 0) ? Wq : (which == 1) ? Wk : Wv;
        do_transpose(src, WqkvT + (size_t)which * DD * DD, DD, DD, 768L * DD,
                     r % 8, (r / 8) % 8, r / 64, tile);
    } else if (b0 < PB_W1) {                  // Wo^T: 384 (8x8x6)
        int r = b0 - PB_WO;
        do_transpose(Wo, WoT, DD, DD, (long)DD * DD, r % 8, (r / 8) % 8, r / 64, tile);
    } else if (b0 < PB_W2) {                  // W1^T: 1536 (8x32x6)
        int r = b0 - PB_W1;
        do_transpose(W1, W1T, DD, DFF, (long)DD * DFF, r % 8, (r / 8) % 32, r / 256, tile);
    } else if (b0 < PB_BIAS) {                // W2^T: 1536 (32x8x6)
        int r = b0 - PB_W2;
        do_transpose(W2, W2T, DFF, DD, (long)DD * DFF, r % 32, (r / 32) % 8, r / 256, tile);
    } else if (b0 < PB_WH1) {                 // pack_bias: 18 blocks
        int idx = (b0 - PB_BIAS) * 256 + t;
        if (idx < LL * 768) {
            int l = idx / 768, c = idx % 768;
            float v = (c < 256) ? bq[l*256 + c] : (c < 512) ? bk[l*256 + c - 256]
                                                            : bv[l*256 + c - 512];
            bqkv[idx] = v;
        }
    } else {                                  // pack_wh1: 384 blocks
        int i = (b0 - PB_WH1) * 256 + t;
        if (i < 384 * 256) {
            int n = i >> 8, k = i & 255;
            float v = (n < 128) ? Wr1[k*128 + n]
                    : (n < 256) ? Wa1[k*128 + (n-128)]
                    : (n < 320) ? Wc1[k*64  + (n-256)]
                                : Wv1[k*64  + (n-320)];
            Wh1T[(size_t)n * 256 + k] = f2bf(v);
        }
        if (i < 384) {
            float v = (i < 128) ? br1[i] : (i < 256) ? ba1[i-128]
                    : (i < 320) ? bc1[i-256] : bv1[i-320];
            bh1[i] = v;
        }
    }
}

// ---------------------------------------------------------------------------
// Single-barrier rotating depth-3 counted-vmcnt bf16 MFMA GEMM (T3+T4):
//   C = epi(A[M,K] @ Wt[N,K]^T + bias)
// 128x128 tile, 2x2 waves (64x64 each), BK=32, chunk-XOR swizzled LDS,
// setprio MFMA, XCD-swizzled grid.
// Loop: wait vmcnt(counted) -> ONE barrier -> ds_read+MFMA -> restage the
// buffer consumed LAST iter (safe: all waves passed this barrier => done
// with it).  Loads stay ~2 stages in flight; vmcnt(0) only on final tile.
// EPI: 0=bias, 1=bias+relu, 2=bias+PE.
// ---------------------------------------------------------------------------
template<int EPI, bool OF32, bool OBF16>
__global__ __launch_bounds__(256)
void mfma_gemm(const u16* __restrict__ A, const u16* __restrict__ Wt,
               const float* __restrict__ bias, const float* __restrict__ pe,
               float* __restrict__ Cf, u16* __restrict__ Cb,
               int M, int N, int K) {
    __shared__ u16 As[3][128 * 32];
    __shared__ u16 Bs[3][128 * 32];
    const int t = threadIdx.x, w = t >> 6, l = t & 63;
    const int bx = xcd_swz(blockIdx.x, gridDim.x);
    const int bm = bx * 128, bn = blockIdx.y * 128;
    const int wr = (w >> 1) * 64, wc = (w & 1) * 64;
    const int lr = l & 15, lq = (l >> 4) * 4;
    const int lks = (((l >> 4) ^ ((lr >> 1) & 3)) * 8);
    const int srow = l >> 2, scol = (((l & 3) ^ ((l >> 3) & 3)) * 8);

    f32x4 acc[4][4] = {};
    const u16* Ag = &A [(size_t)(bm + w * 32 + srow) * K + scol];
    const u16* Bg = &Wt[(size_t)(bn + w * 32 + srow) * K + scol];

    auto stage = [&](int buf, int k0) {   // 4 loads per wave per stage
        gload16(Ag + k0,                  &As[buf][(w * 32) * 32]);
        gload16(Ag + k0 + (size_t)16 * K, &As[buf][(w * 32 + 16) * 32]);
        gload16(Bg + k0,                  &Bs[buf][(w * 32) * 32]);
        gload16(Bg + k0 + (size_t)16 * K, &Bs[buf][(w * 32 + 16) * 32]);
    };

    const int tiles = K >> 5;
    stage(0, 0);
    if (tiles > 1) stage(1, 32);
    if (tiles > 2) stage(2, 64);
    int cur = 0;

    for (int i = 0; i < tiles; ++i) {
        const int k0 = i << 5;
        if (i == tiles - 1)      asm volatile("s_waitcnt vmcnt(0)" ::: "memory");
        else if (i == 0) {
            if (tiles > 2)       asm volatile("s_waitcnt vmcnt(8)" ::: "memory");
            else                 asm volatile("s_waitcnt vmcnt(4)" ::: "memory");
        } else                   asm volatile("s_waitcnt vmcnt(4)" ::: "memory");
        __builtin_amdgcn_s_barrier();      // cur landed everywhere; prev free

        bf16x8 af[4], bfr[4];
#pragma unroll
        for (int m = 0; m < 4; ++m) af[m]  = *(const bf16x8*)&As[cur][(wr + m*16 + lr) * 32 + lks];
#pragma unroll
        for (int n = 0; n < 4; ++n) bfr[n] = *(const bf16x8*)&Bs[cur][(wc + n*16 + lr) * 32 + lks];
        __builtin_amdgcn_s_setprio(1);
#pragma unroll
        for (int m = 0; m < 4; ++m)
#pragma unroll
            for (int n = 0; n < 4; ++n)
                acc[m][n] = MFMA16(af[m], bfr[n], acc[m][n]);
        __builtin_amdgcn_s_setprio(0);

        // restage buffer consumed last iter with tile i+2 (exists iff k0+64<K)
        if (i >= 1 && k0 + 64 < K) stage((cur + 2) % 3, k0 + 64);
        cur = (cur == 2) ? 0 : cur + 1;
    }

    // C/D layout: col=lane&15, row=(lane>>4)*4+j
#pragma unroll
    for (int n = 0; n < 4; ++n) {
        const int col = bn + wc + n*16 + lr;
        const float bv = bias[col];
#pragma unroll
        for (int m = 0; m < 4; ++m) {
#pragma unroll
            for (int j = 0; j < 4; ++j) {
                const int row = bm + wr + m*16 + lq + j;
                float v = acc[m][n][j] + bv;
                if (EPI == 1) v = fmaxf(v, 0.f);
                if (EPI == 2) v += pe[(row % SS) * DD + col];
                if (OF32)  Cf[(size_t)row * N + col] = v;
                if (OBF16) Cb[(size_t)row * N + col] = f2bf(v);
            }
        }
    }
}

// ---------------------------------------------------------------------------
// Single-barrier rotating depth-3 fused GEMM + bias + residual + LN,
// 8 waves (512 thr), chunk-XOR swizzled LDS, setprio, XCD swizzle:
//   y = LN(bf16_resid + A@Wt^T + bias)*g + be -> hb (bf16, sole stream)
// Tile 64 rows x 256 cols, wave grid 2x4 (each wave 32x64, acc 2x4).
// Staging: 20 chunks (A:4, B:16); waves 0-3 stage 3, waves 4-7 stage 2.
// ---------------------------------------------------------------------------
__global__ __launch_bounds__(512)
void gemm_ln(const u16* __restrict__ A, const u16* __restrict__ Wt,
             const float* __restrict__ bias, const float* __restrict__ g,
             const float* __restrict__ be, u16* __restrict__ hb, int K) {
    __shared__ u16 As[3][64 * 32];
    __shared__ u16 Bs[3][256 * 32];
    __shared__ float red[64][8];   // [row][wc*2 + {s1,s2}]
    const int t = threadIdx.x, w = t >> 6, l = t & 63;
    const int bm = xcd_swz(blockIdx.x, gridDim.x) * 64;
    const int wr = w >> 2, wc = w & 3;
    const int lr = l & 15, lq = (l >> 4) * 4;
    const int lks = (((l >> 4) ^ ((lr >> 1) & 3)) * 8);
    const int crow = l >> 2, ccol = (((l & 3) ^ ((l >> 3) & 3)) * 8);

    // staging chunk assignment (wave-uniform): waves 0-3 -> 3 chunks, 4-7 -> 2
    const int c0 = (w < 4) ? 3*w : 12 + 2*(w - 4);
    const int nc = (w < 4) ? 3 : 2;

    f32x4 acc[2][4] = {};

    auto stage = [&](int buf, int k0) {
        for (int ci = 0; ci < nc; ++ci) {
            const int c = c0 + ci;
            if (c < 4)
                gload16(&A [(size_t)(bm + c*16 + crow) * K + k0 + ccol], &As[buf][c*16*32]);
            else
                gload16(&Wt[(size_t)((c-4)*16 + crow) * K + k0 + ccol], &Bs[buf][(c-4)*16*32]);
        }
    };

    const int tiles = K >> 5;
    stage(0, 0);
    if (tiles > 1) stage(1, 32);
    if (tiles > 2) stage(2, 64);
    int cur = 0;

    for (int i = 0; i < tiles; ++i) {
        const int k0 = i << 5;
        if (i == tiles - 1) {
            asm volatile("s_waitcnt vmcnt(0)" ::: "memory");
        } else if (i == 0 && tiles > 2) {
            if (w < 4) asm volatile("s_waitcnt vmcnt(6)" ::: "memory");
            else       asm volatile("s_waitcnt vmcnt(4)" ::: "memory");
        } else {
            if (w < 4) asm volatile("s_waitcnt vmcnt(3)" ::: "memory");
            else       asm volatile("s_waitcnt vmcnt(2)" ::: "memory");
        }
        __builtin_amdgcn_s_barrier();      // cur landed everywhere; prev free

        bf16x8 af[2], bf[4];
#pragma unroll
        for (int mf = 0; mf < 2; ++mf) af[mf] = *(const bf16x8*)&As[cur][(wr*32 + mf*16 + lr) * 32 + lks];
#pragma unroll
        for (int n = 0; n < 4; ++n)    bf[n]  = *(const bf16x8*)&Bs[cur][(wc*64 + n*16 + lr) * 32 + lks];
        __builtin_amdgcn_s_setprio(1);
#pragma unroll
        for (int mf = 0; mf < 2; ++mf)
#pragma unroll
            for (int n = 0; n < 4; ++n)
                acc[mf][n] = MFMA16(af[mf], bf[n], acc[mf][n]);
        __builtin_amdgcn_s_setprio(0);

        if (i >= 1 && k0 + 64 < K) stage((cur + 2) % 3, k0 + 64);
        cur = (cur == 2) ? 0 : cur + 1;
    }

    float bv[4], gv[4], bev[4];
#pragma unroll
    for (int n = 0; n < 4; ++n) {
        int col = wc*64 + n*16 + lr;
        bv[n] = bias[col]; gv[n] = g[col]; bev[n] = be[col];
    }
    // pass 1: add bias + bf16 residual, partial row sums over wave's 64 cols
#pragma unroll
    for (int mf = 0; mf < 2; ++mf) {
#pragma unroll
        for (int j = 0; j < 4; ++j) {
            const int rloc = wr*32 + mf*16 + lq + j;
            const int row  = bm + rloc;
            float s1 = 0.f, s2 = 0.f;
#pragma unroll
            for (int n = 0; n < 4; ++n) {
                float v = acc[mf][n][j] + bv[n] + bf2f(hb[(size_t)row * DD + wc*64 + n*16 + lr]);
                acc[mf][n][j] = v;
                s1 += v; s2 += v * v;
            }
            s1 += __shfl_xor(s1, 1); s2 += __shfl_xor(s2, 1);
            s1 += __shfl_xor(s1, 2); s2 += __shfl_xor(s2, 2);
            s1 += __shfl_xor(s1, 4); s2 += __shfl_xor(s2, 4);
            s1 += __shfl_xor(s1, 8); s2 += __shfl_xor(s2, 8);
            if (lr == 0) { red[rloc][wc*2] = s1; red[rloc][wc*2+1] = s2; }
        }
    }
    __syncthreads();
    // pass 2: normalize + store bf16
#pragma unroll
    for (int mf = 0; mf < 2; ++mf) {
#pragma unroll
        for (int j = 0; j < 4; ++j) {
            const int rloc = wr*32 + mf*16 + lq + j;
            const int row  = bm + rloc;
            float s1 = red[rloc][0] + red[rloc][2] + red[rloc][4] + red[rloc][6];
            float s2 = red[rloc][1] + red[rloc][3] + red[rloc][5] + red[rloc][7];
            float mean = s1 * (1.f/DD);
            float var  = s2 * (1.f/DD) - mean*mean;
            float rstd = rsqrtf(var + 1e-5f);
#pragma unroll
            for (int n = 0; n < 4; ++n) {
                int col = wc*64 + n*16 + lr;
                float y = (acc[mf][n][j] - mean) * rstd * gv[n] + bev[n];
                hb[(size_t)row * DD + col] = f2bf(y);
            }
        }
    }
}

// ---------------------------------------------------------------------------
// MFMA attention: one block per (b,h), 4 waves (wave w owns q-rows 32w..32w+32).
// Q/K frags straight from global. V transposed to LDS via coalesced loads.
// ---------------------------------------------------------------------------
__global__ __launch_bounds__(256)
void attn_mfma(const u16* __restrict__ qkv, u16* __restrict__ ao) {
    const int b = blockIdx.x >> 3, hh = blockIdx.x & 7;
    const int t = threadIdx.x, w = t >> 6, l = t & 63;
    const int lr = l & 15, lk = (l >> 4) * 8, lq = (l >> 4) * 4;
    __shared__ u16 Vt[32 * 136];          // V^T[d][s], s padded/zeroed to 136
    __shared__ u16 Ps[4][32 * 136];
    const size_t rbase = (size_t)b * SS * 768;
    const int qc = hh * 32, kc = 256 + hh * 32, vc = 512 + hh * 32;

    // V stage: coalesced row loads, transpose in regs -> LDS
    for (int u = t; u < 400; u += 256) {           // 100 rows x 4 chunks of 8
        int s = u >> 2, dp = (u & 3) * 8;
        u16x8 vv = *(const u16x8*)&qkv[rbase + (size_t)s * 768 + vc + dp];
#pragma unroll
        for (int e = 0; e < 8; ++e) Vt[(dp + e) * 136 + s] = vv[e];
    }
    for (int i = t; i < 32 * 36; i += 256) {       // zero pad s=100..135
        int d = i / 36, s2 = 100 + i % 36;
        Vt[d * 136 + s2] = 0;
    }

    // Q fragments direct from global
    u16x8 qz = {0,0,0,0,0,0,0,0};
    u16x8 qfr[2];
#pragma unroll
    for (int m = 0; m < 2; ++m) {
        int r = w * 32 + m * 16 + lr;
        qfr[m] = (r < SS) ? *(const u16x8*)&qkv[rbase + (size_t)r * 768 + qc + lk] : qz;
    }

    // S = Q K^T
    f32x4 sacc[2][7] = {};
#pragma unroll
    for (int n = 0; n < 7; ++n) {
        int r = n * 16 + lr;
        u16x8 kfr = (r < SS) ? *(const u16x8*)&qkv[rbase + (size_t)r * 768 + kc + lk] : qz;
#pragma unroll
        for (int m = 0; m < 2; ++m)
            sacc[m][n] = MFMA16(*(bf16x8*)&qfr[m], *(bf16x8*)&kfr, sacc[m][n]);
    }

    // softmax per row (cols n*16+lr; cols>=100 masked)
#pragma unroll
    for (int m = 0; m < 2; ++m) {
#pragma unroll
        for (int j = 0; j < 4; ++j) {
            float mx = -1e30f;
#pragma unroll
            for (int n = 0; n < 7; ++n) {
                float s = sacc[m][n][j] * INV_SCALE;
                if (n == 6 && lr >= 4) s = -1e30f;
                sacc[m][n][j] = s;
                mx = fmaxf(mx, s);
            }
            mx = fmaxf(mx, __shfl_xor(mx, 1));
            mx = fmaxf(mx, __shfl_xor(mx, 2));
            mx = fmaxf(mx, __shfl_xor(mx, 4));
            mx = fmaxf(mx, __shfl_xor(mx, 8));
            float sum = 0.f;
#pragma unroll
            for (int n = 0; n < 7; ++n) {
                float p = expf(sacc[m][n][j] - mx);
                if (n == 6 && lr >= 4) p = 0.f;
                sacc[m][n][j] = p;
                sum += p;
            }
            sum += __shfl_xor(sum, 1);
            sum += __shfl_xor(sum, 2);
            sum += __shfl_xor(sum, 4);
            sum += __shfl_xor(sum, 8);
            float inv = 1.f / sum;
#pragma unroll
            for (int n = 0; n < 7; ++n) sacc[m][n][j] *= inv;
        }
    }

    // P -> LDS (bf16), wave-private; zero pad cols 112..135
    u16* myP = &Ps[w][0];
    for (int i = l; i < 32 * 24; i += 64) {
        int r = i / 24, c2 = 112 + i % 24;
        myP[r * 136 + c2] = 0;
    }
#pragma unroll
    for (int m = 0; m < 2; ++m)
#pragma unroll
        for (int n = 0; n < 7; ++n)
#pragma unroll
            for (int j = 0; j < 4; ++j)
                myP[(m*16 + lq + j) * 136 + n*16 + lr] = f2bf(sacc[m][n][j]);

    __syncthreads();   // Vt + Ps visible

    // O = P @ V
    f32x4 oacc[2][2] = {};
#pragma unroll
    for (int ks = 0; ks < 4; ++ks) {
        bf16x8 pf[2], vf[2];
#pragma unroll
        for (int m = 0; m < 2; ++m) pf[m] = *(const bf16x8*)&myP[(m*16 + lr) * 136 + ks*32 + lk];
#pragma unroll
        for (int n = 0; n < 2; ++n) vf[n] = *(const bf16x8*)&Vt [(n*16 + lr) * 136 + ks*32 + lk];
#pragma unroll
        for (int m = 0; m < 2; ++m)
#pragma unroll
            for (int n = 0; n < 2; ++n)
                oacc[m][n] = MFMA16(pf[m], vf[n], oacc[m][n]);
    }
#pragma unroll
    for (int m = 0; m < 2; ++m)
#pragma unroll
        for (int j = 0; j < 4; ++j) {
            int s = w*32 + m*16 + lq + j;
            if (s < SS) {
#pragma unroll
                for (int n = 0; n < 2; ++n)
                    ao[((size_t)(b*SS + s)) * DD + hh*32 + n*16 + lr] = f2bf(oacc[m][n][j]);
            }
        }
}

// ---------------------------------------------------------------------------
// Final LN on last row of each batch only (reads bf16 hb, stats in fp32).
// ---------------------------------------------------------------------------
__global__ __launch_bounds__(256)
void lastrow_ln(const u16* __restrict__ hb, const float* __restrict__ g,
                const float* __restrict__ be, float* __restrict__ out,
                u16* __restrict__ hfb) {
    const int b = blockIdx.x;
    const int c = threadIdx.x;
    float x = bf2f(hb[(size_t)(b * SS + SS - 1) * DD + c]);

    float s1 = x, s2 = x * x;
#pragma unroll
    for (int o = 32; o > 0; o >>= 1) {
        s1 += __shfl_down(s1, o);
        s2 += __shfl_down(s2, o);
    }
    __shared__ float w1[4], w2[4];
    __shared__ float mean_s, rstd_s;
    const int wid = c >> 6, lane = c & 63;
    if (lane == 0) { w1[wid] = s1; w2[wid] = s2; }
    __syncthreads();
    if (c == 0) {
        float t1 = w1[0] + w1[1] + w1[2] + w1[3];
        float t2 = w2[0] + w2[1] + w2[2] + w2[3];
        float m = t1 * (1.0f / DD);
        float v = t2 * (1.0f / DD) - m * m;
        mean_s = m;
        rstd_s = rsqrtf(v + 1e-5f);
    }
    __syncthreads();
    float y = (x - mean_s) * rstd_s * g[c] + be[c];
    out[1536 + b * DD + c] = y;
    hfb[b * DD + c] = f2bf(y);
}

// ---------------------------------------------------------------------------
// Heads layer-2+: reads t1f[b][384] = relu([r1|a1|c1|v1]), finishes all heads.
// ---------------------------------------------------------------------------
__global__ __launch_bounds__(256)
void heads2_kernel(const float* __restrict__ t1f,
                   const float* __restrict__ Wr2, const float* __restrict__ br2,
                   const float* __restrict__ Wa2, const float* __restrict__ ba2,
                   const float* __restrict__ Wa3, const float* __restrict__ ba3,
                   const float* __restrict__ Wc2, const float* __restrict__ bc2,
                   const float* __restrict__ Wv2, const float* __restrict__ bv2,
                   float* __restrict__ out) {
    const int b = blockIdx.x, t = threadIdx.x;
    __shared__ float t1[384];
    __shared__ float a2[64];
    __shared__ float lg[3];
    for (int i = t; i < 384; i += 256) t1[i] = t1f[(size_t)b * 384 + i];
    __syncthreads();

    if (t < 64) {                       // action layer 2 (128 -> 64), relu
        float acc = ba2[t];
        for (int k = 0; k < 128; ++k) acc = fmaf(t1[128 + k], Wa2[k * 64 + t], acc);
        a2[t] = fmaxf(acc, 0.f);
    } else if (t == 64) {               // confidence (64 -> 1), sigmoid
        float acc = bc2[0];
        for (int k = 0; k < 64; ++k) acc = fmaf(t1[256 + k], Wc2[k], acc);
        out[1024 + b] = 1.0f / (1.0f + expf(-acc));
    } else if (t == 65) {               // volatility (64 -> 1), relu
        float acc = bv2[0];
        for (int k = 0; k < 64; ++k) acc = fmaf(t1[320 + k], Wv2[k], acc);
        out[1280 + b] = fmaxf(acc, 0.f);
    } else if (t >= 66 && t < 69) {     // regime logits (128 -> 3)
        int r = t - 66;
        float acc = br2[r];
        for (int k = 0; k < 128; ++k) acc = fmaf(t1[k], Wr2[k * 3 + r], acc);
        lg[r] = acc;
    }
    __syncthreads();
    if (t == 0) {                       // regime softmax
        float m = fmaxf(lg[0], fmaxf(lg[1], lg[2]));
        float e0 = expf(lg[0] - m), e1 = expf(lg[1] - m), e2 = expf(lg[2] - m);
        float inv = 1.0f / (e0 + e1 + e2);
        out[256 + b * 3 + 0] = e0 * inv;
        out[256 + b * 3 + 1] = e1 * inv;
        out[256 + b * 3 + 2] = e2 * inv;
    }
    if (t < 64) {                       // action layer 3 (64 -> 1), tanh
        float p = a2[t] * Wa3[t];
        p += __shfl_xor(p, 1);
        p += __shfl_xor(p, 2);
        p += __shfl_xor(p, 4);
        p += __shfl_xor(p, 8);
        p += __shfl_xor(p, 16);
        p += __shfl_xor(p, 32);
        if (t == 0) out[b] = tanhf(p + ba3[0]);
    }
}

// ---------------------------------------------------------------------------
// Launch
// ---------------------------------------------------------------------------
extern "C" void kernel_launch(void* const* d_in, const int* in_sizes, int n_in,
                              void* d_out, int out_size, void* d_ws, size_t ws_size,
                              hipStream_t stream) {
    const float* x    = (const float*)d_in[0];
    const float* W_in = (const float*)d_in[1];
    const float* b_in = (const float*)d_in[2];
    const float* Wq   = (const float*)d_in[3];
    const float* bq   = (const float*)d_in[4];
    const float* Wk   = (const float*)d_in[5];
    const float* bk   = (const float*)d_in[6];
    const float* Wv   = (const float*)d_in[7];
    const float* bv   = (const float*)d_in[8];
    const float* Wo   = (const float*)d_in[9];
    const float* bo   = (const float*)d_in[10];
    const float* g1   = (const float*)d_in[11];
    const float* be1  = (const float*)d_in[12];
    const float* W1   = (const float*)d_in[13];
    const float* b1   = (const float*)d_in[14];
    const float* W2   = (const float*)d_in[15];
    const float* b2   = (const float*)d_in[16];
    const float* g2   = (const float*)d_in[17];
    const float* be2  = (const float*)d_in[18];
    const float* lnf_g = (const float*)d_in[19];
    const float* lnf_b = (const float*)d_in[20];
    const float* Wr1  = (const float*)d_in[21];
    const float* br1  = (const float*)d_in[22];
    const float* Wr2  = (const float*)d_in[23];
    const float* br2  = (const float*)d_in[24];
    const float* Wa1  = (const float*)d_in[25];
    const float* ba1  = (const float*)d_in[26];
    const float* Wa2  = (const float*)d_in[27];
    const float* ba2  = (const float*)d_in[28];
    const float* Wa3  = (const float*)d_in[29];
    const float* ba3  = (const float*)d_in[30];
    const float* Wc1  = (const float*)d_in[31];
    const float* bc1  = (const float*)d_in[32];
    const float* Wc2  = (const float*)d_in[33];
    const float* bc2  = (const float*)d_in[34];
    const float* Wv1  = (const float*)d_in[35];
    const float* bv1  = (const float*)d_in[36];
    const float* Wv2  = (const float*)d_in[37];
    const float* bv2  = (const float*)d_in[38];
    float* out = (float*)d_out;

    // workspace layout
    char* w8 = (char*)d_ws;
    float* pe    = (float*)w8;  w8 += (size_t)SS * DD * 4;
    u16*   hb    = (u16*)w8;    w8 += (size_t)MM * DD * 2;
    u16*   xb    = (u16*)w8;    w8 += (size_t)MM * DIN * 2;
    u16*   qkvb  = (u16*)w8;    w8 += (size_t)MM * 768 * 2;
    u16*   ao    = (u16*)w8;    w8 += (size_t)MM * DD * 2;
    u16*   ffn1b = (u16*)w8;    w8 += (size_t)MM * DFF * 2;
    u16*   WinT  = (u16*)w8;    w8 += (size_t)DIN * DD * 2;
    u16*   WqkvT = (u16*)w8;    w8 += (size_t)LL * 768 * DD * 2;
    u16*   WoT   = (u16*)w8;    w8 += (size_t)LL * DD * DD * 2;
    u16*   W1T   = (u16*)w8;    w8 += (size_t)LL * DFF * DD * 2;
    u16*   W2T   = (u16*)w8;    w8 += (size_t)LL * DD * DFF * 2;
    float* bqkv  = (float*)w8;  w8 += (size_t)LL * 768 * 4;
    u16*   Wh1T  = (u16*)w8;    w8 += (size_t)384 * 256 * 2;
    float* bh1   = (float*)w8;  w8 += (size_t)384 * 4;
    u16*   hfb   = (u16*)w8;    w8 += (size_t)BB * DD * 2;
    float* t1f   = (float*)w8;  w8 += (size_t)BB * 384 * 4;

    // fused prep (replaces 11 serial dispatches)
    prep_all<<<PB_TOT, 256, 0, stream>>>(
        x, W_in, Wq, Wk, Wv, Wo, W1, W2, bq, bk, bv,
        Wr1, Wa1, Wc1, Wv1, br1, ba1, bc1, bv1,
        pe, xb, WinT, WqkvT, WoT, W1T, W2T, bqkv, Wh1T, bh1);

    // input projection + PE  -> hb (bf16 residual stream)
    mfma_gemm<2, false, true><<<dim3(MM/128, DD/128), 256, 0, stream>>>(
        xb, WinT, b_in, pe, nullptr, hb, MM, DD, DIN);

    for (int l = 0; l < LL; ++l) {
        mfma_gemm<0, false, true><<<dim3(MM/128, 768/128), 256, 0, stream>>>(
            hb, WqkvT + (size_t)l*768*DD, bqkv + l*768, nullptr, nullptr, qkvb, MM, 768, DD);
        attn_mfma<<<BB * HH, 256, 0, stream>>>(qkvb, ao);
        gemm_ln<<<MM/64, 512, 0, stream>>>(
            ao, WoT + (size_t)l*DD*DD, bo + l*DD, g1 + l*DD, be1 + l*DD, hb, DD);
        mfma_gemm<1, false, true><<<dim3(MM/128, DFF/128), 256, 0, stream>>>(
            hb, W1T + (size_t)l*DFF*DD, b1 + l*DFF, nullptr, nullptr, ffn1b, MM, DFF, DD);
        gemm_ln<<<MM/64, 512, 0, stream>>>(
            ffn1b, W2T + (size_t)l*DD*DFF, b2 + l*DD, g2 + l*DD, be2 + l*DD, hb, DFF);
    }

    // final LN: only the last row per batch is consumed downstream
    lastrow_ln<<<BB, 256, 0, stream>>>(hb, lnf_g, lnf_b, out, hfb);

    // heads layer 1 as one MFMA GEMM (relu): [256,256] @ [256,384]^T
    mfma_gemm<1, true, false><<<dim3(2, 3), 256, 0, stream>>>(
        hfb, Wh1T, bh1, nullptr, t1f, nullptr, 256, 384, 256);

    // heads layer 2+
    heads2_kernel<<<BB, 256, 0, stream>>>(t1f,
        Wr2, br2, Wa2, ba2, Wa3, ba3, Wc2, bc2, Wv2, bv2, out);
}